// Round 1
// baseline (677.463 us; speedup 1.0000x reference)
//
#include <hip/hip_runtime.h>

#define NTAGS 128
#define BB    256
#define SS    512

__global__ void zero_out_kernel(float* out) { out[0] = 0.0f; }

__global__ __launch_bounds__(256) void crf_fwd_kernel(
    const float* __restrict__ emissions,        // [B, S, NTAGS] f32
    const int* __restrict__ tags,               // [B, S] int32
    const unsigned char* __restrict__ mask,     // [B, S] bool (1 byte)
    const float* __restrict__ trans,            // [NTAGS, NTAGS] f32
    float* __restrict__ out)                    // [1] f32
{
    const int b    = blockIdx.x;
    const int tid  = threadIdx.x;
    const int j    = tid & (NTAGS - 1);
    const int half = tid >> 7;                  // 0 or 1

    __shared__ float p_sh[NTAGS];
    __shared__ float sHi[NTAGS];
    __shared__ float red[4];
    __shared__ int   tags_sh[SS];
    __shared__ float mask_sh[SS];

    // ---- stage tags / mask for this batch ----
    for (int t = tid; t < SS; t += 256) {
        tags_sh[t] = tags[b * SS + t];
        mask_sh[t] = mask[b * SS + t] ? 1.0f : 0.0f;
    }

    // ---- expT in registers: eT[k] = exp(T[half*64+k][j]) ----
    float eT[64];
    #pragma unroll
    for (int k = 0; k < 64; k++) {
        eT[k] = __expf(trans[(half * 64 + k) * NTAGS + j]);
    }

    __syncthreads();   // tags_sh / mask_sh ready

    // ---- gold transition score, parallel over threads ----
    float gold = 0.0f;
    for (int t = 1 + tid; t < SS; t += 256) {
        gold += trans[tags_sh[t - 1] * NTAGS + tags_sh[t]] * mask_sh[t];
    }

    // ---- alpha init (t = 0): alpha[j] = emissions[b,0,j] ----
    const float* emB = emissions + (size_t)b * SS * NTAGS;
    float alpha = 0.0f;
    if (tid < NTAGS) {
        alpha = emB[j];
        if (j == tags_sh[0]) gold += alpha * mask_sh[0];
    }

    // ---- forward recursion ----
    for (int t = 1; t < SS; t++) {
        // prefetch this step's emissions early (used at end of step)
        float e_t = 0.0f;
        if (tid < NTAGS) e_t = emB[t * NTAGS + j];

        // max over alpha (held in registers of threads 0..127)
        if (tid < NTAGS) {
            float v = alpha;
            #pragma unroll
            for (int o = 32; o > 0; o >>= 1) v = fmaxf(v, __shfl_xor(v, o));
            if ((tid & 63) == 0) red[tid >> 6] = v;
        }
        __syncthreads();                         // sync1: red ready

        float m = 0.0f;
        if (tid < NTAGS) {
            m = fmaxf(red[0], red[1]);
            p_sh[j] = __expf(alpha - m);
        }
        __syncthreads();                         // sync2: p ready

        // matvec partial: s_part[j] = sum_{k=0..63} p[half*64+k] * eT[k]
        const float4* p4 = (const float4*)(p_sh + half * 64);
        float a0 = 0.f, a1 = 0.f, a2 = 0.f, a3 = 0.f;
        #pragma unroll
        for (int k = 0; k < 16; k++) {
            float4 pv = p4[k];                   // broadcast (same addr per wave)
            a0 = fmaf(pv.x, eT[4 * k + 0], a0);
            a1 = fmaf(pv.y, eT[4 * k + 1], a1);
            a2 = fmaf(pv.z, eT[4 * k + 2], a2);
            a3 = fmaf(pv.w, eT[4 * k + 3], a3);
        }
        float s = (a0 + a1) + (a2 + a3);
        if (half) sHi[j] = s;
        __syncthreads();                         // sync3: sHi ready

        if (tid < NTAGS) {
            float stot = s + sHi[j];
            alpha = m + __logf(stot) + e_t;
            if (j == tags_sh[t]) gold += e_t * mask_sh[t];
        }
    }

    // ---- epilogue: partition_b = logsumexp(alpha), block-reduce gold ----
    {
        float g = gold;
        #pragma unroll
        for (int o = 32; o > 0; o >>= 1) g += __shfl_xor(g, o);
        if ((tid & 63) == 0) p_sh[tid >> 6] = g;     // wave gold sums (4 waves)
    }
    if (tid < NTAGS) {
        float w = alpha;
        #pragma unroll
        for (int o = 32; o > 0; o >>= 1) w = fmaxf(w, __shfl_xor(w, o));
        if ((tid & 63) == 0) red[tid >> 6] = w;
    }
    __syncthreads();
    if (tid < NTAGS) {
        float m = fmaxf(red[0], red[1]);
        float v = __expf(alpha - m);
        #pragma unroll
        for (int o = 32; o > 0; o >>= 1) v += __shfl_xor(v, o);
        if ((tid & 63) == 0) sHi[tid >> 6] = v;      // wave expsums (2 waves)
        if (tid == 0) red[2] = m;
    }
    __syncthreads();
    if (tid == 0) {
        float part  = red[2] + __logf(sHi[0] + sHi[1]);
        float goldT = p_sh[0] + p_sh[1] + p_sh[2] + p_sh[3];
        atomicAdd(out, part - goldT);
    }
}

extern "C" void kernel_launch(void* const* d_in, const int* in_sizes, int n_in,
                              void* d_out, int out_size, void* d_ws, size_t ws_size,
                              hipStream_t stream) {
    const float*         emissions = (const float*)d_in[0];
    const int*           tags      = (const int*)d_in[1];
    const unsigned char* mask      = (const unsigned char*)d_in[2];
    const float*         trans     = (const float*)d_in[3];
    float*               out       = (float*)d_out;

    zero_out_kernel<<<1, 1, 0, stream>>>(out);
    crf_fwd_kernel<<<BB, 256, 0, stream>>>(emissions, tags, mask, trans, out);
}

// Round 2
// 439.821 us; speedup vs baseline: 1.5403x; 1.5403x over previous
//
#include <hip/hip_runtime.h>

#define NTAGS 128
#define BB    256
#define SS    512

typedef float f32x2 __attribute__((ext_vector_type(2)));

__global__ void zero_out_kernel(float* out) { out[0] = 0.0f; }

__global__ __launch_bounds__(128, 1) void crf_fwd_kernel(
    const float* __restrict__ emissions,        // [B, S, NTAGS] f32
    const int* __restrict__ tags,               // [B, S] int32
    const unsigned char* __restrict__ mask,     // [B, S] bool
    const float* __restrict__ trans,            // [NTAGS, NTAGS] f32
    float* __restrict__ out)                    // [1] f32
{
    const int b = blockIdx.x;
    const int j = threadIdx.x;            // 0..127 — owns column j
    const int w = j >> 6;                 // wave id 0/1

    __shared__ float p_sh[2][NTAGS];      // parity double-buffered p
    __shared__ float mbuf[2][2];          // parity double-buffered wave maxes
    __shared__ int   tags_sh[SS];
    __shared__ float mask_sh[SS];
    __shared__ float red_sh[4];

    // ---- stage tags / mask ----
    for (int t = j; t < SS; t += 128) {
        tags_sh[t] = tags[b * SS + t];
        mask_sh[t] = mask[b * SS + t] ? 1.0f : 0.0f;
    }

    // ---- expT column j in registers, packed in pairs over i ----
    f32x2 eT2[64];
    #pragma unroll
    for (int k = 0; k < 64; k++) {
        f32x2 v;
        v.x = __expf(trans[(2 * k + 0) * NTAGS + j]);
        v.y = __expf(trans[(2 * k + 1) * NTAGS + j]);
        eT2[k] = v;
    }

    __syncthreads();  // tags_sh / mask_sh ready

    // ---- gold transition score (parallel over threads) ----
    float gold = 0.0f;
    for (int t = 1 + j; t < SS; t += 128)
        gold += trans[tags_sh[t - 1] * NTAGS + tags_sh[t]] * mask_sh[t];

    const float* emB = emissions + (size_t)b * SS * NTAGS;
    float alpha = emB[j];
    if (j == tags_sh[0]) gold += alpha * mask_sh[0];

    // ---- initial per-wave max of alpha0 ----
    float Mw;
    {
        float v = alpha;
        #pragma unroll
        for (int o = 32; o > 0; o >>= 1) v = fmaxf(v, __shfl_xor(v, o));
        Mw = v;
    }

    // ---- emission register pipeline (depth 2) ----
    float eO = emB[1 * NTAGS + j];   // for t = 1
    float eE = emB[2 * NTAGS + j];   // for t = 2

    // ---- forward recursion: one barrier per step ----
    for (int t = 1; t < SS; t += 2) {
        // ======== odd step t (parity q=1) ========
        {
            float p = __expf(alpha - Mw);
            p_sh[1][j] = p;
            if ((j & 63) == 0) mbuf[1][w] = Mw;
            // stale max for step t+1 — off the critical chain
            float v = alpha;
            #pragma unroll
            for (int o = 32; o > 0; o >>= 1) v = fmaxf(v, __shfl_xor(v, o));
            float Mn = v;
            __syncthreads();
            float m0 = mbuf[1][0], m1 = mbuf[1][1];
            float mm = fmaxf(m0, m1);
            float f0 = __expf(m0 - mm), f1 = __expf(m1 - mm);

            const float4* p4 = (const float4*)(p_sh[1]);
            f32x2 aA0 = {0.f, 0.f}, aA1 = {0.f, 0.f};
            f32x2 aB0 = {0.f, 0.f}, aB1 = {0.f, 0.f};
            #pragma unroll
            for (int k = 0; k < 16; k++) {          // i = 0..63 (scaled by m0)
                float4 pv = p4[k];
                f32x2 lo = {pv.x, pv.y}, hi = {pv.z, pv.w};
                aA0 = __builtin_elementwise_fma(lo, eT2[2 * k + 0], aA0);
                aA1 = __builtin_elementwise_fma(hi, eT2[2 * k + 1], aA1);
            }
            #pragma unroll
            for (int k = 16; k < 32; k++) {         // i = 64..127 (scaled by m1)
                float4 pv = p4[k];
                f32x2 lo = {pv.x, pv.y}, hi = {pv.z, pv.w};
                aB0 = __builtin_elementwise_fma(lo, eT2[2 * k + 0], aB0);
                aB1 = __builtin_elementwise_fma(hi, eT2[2 * k + 1], aB1);
            }
            float sA = (aA0.x + aA0.y) + (aA1.x + aA1.y);
            float sB = (aB0.x + aB0.y) + (aB1.x + aB1.y);

            float e_t = eO;
            int tn = t + 2; if (tn > SS - 1) tn = SS - 1;
            eO = emB[(size_t)tn * NTAGS + j];

            alpha = mm + __logf(fmaf(sA, f0, sB * f1)) + e_t;
            if (j == tags_sh[t]) gold += e_t * mask_sh[t];
            Mw = Mn;
        }
        // ======== even step t+1 (parity q=0) ========
        if (t + 1 < SS) {
            float p = __expf(alpha - Mw);
            p_sh[0][j] = p;
            if ((j & 63) == 0) mbuf[0][w] = Mw;
            float v = alpha;
            #pragma unroll
            for (int o = 32; o > 0; o >>= 1) v = fmaxf(v, __shfl_xor(v, o));
            float Mn = v;
            __syncthreads();
            float m0 = mbuf[0][0], m1 = mbuf[0][1];
            float mm = fmaxf(m0, m1);
            float f0 = __expf(m0 - mm), f1 = __expf(m1 - mm);

            const float4* p4 = (const float4*)(p_sh[0]);
            f32x2 aA0 = {0.f, 0.f}, aA1 = {0.f, 0.f};
            f32x2 aB0 = {0.f, 0.f}, aB1 = {0.f, 0.f};
            #pragma unroll
            for (int k = 0; k < 16; k++) {
                float4 pv = p4[k];
                f32x2 lo = {pv.x, pv.y}, hi = {pv.z, pv.w};
                aA0 = __builtin_elementwise_fma(lo, eT2[2 * k + 0], aA0);
                aA1 = __builtin_elementwise_fma(hi, eT2[2 * k + 1], aA1);
            }
            #pragma unroll
            for (int k = 16; k < 32; k++) {
                float4 pv = p4[k];
                f32x2 lo = {pv.x, pv.y}, hi = {pv.z, pv.w};
                aB0 = __builtin_elementwise_fma(lo, eT2[2 * k + 0], aB0);
                aB1 = __builtin_elementwise_fma(hi, eT2[2 * k + 1], aB1);
            }
            float sA = (aA0.x + aA0.y) + (aA1.x + aA1.y);
            float sB = (aB0.x + aB0.y) + (aB1.x + aB1.y);

            float e_t = eE;
            int tn = t + 3; if (tn > SS - 1) tn = SS - 1;
            eE = emB[(size_t)tn * NTAGS + j];

            alpha = mm + __logf(fmaf(sA, f0, sB * f1)) + e_t;
            if (j == tags_sh[t + 1]) gold += e_t * mask_sh[t + 1];
            Mw = Mn;
        }
    }

    // ---- epilogue: partition_b = logsumexp(alpha); reduce gold ----
    {
        float g = gold;
        #pragma unroll
        for (int o = 32; o > 0; o >>= 1) g += __shfl_xor(g, o);
        float v = alpha;
        #pragma unroll
        for (int o = 32; o > 0; o >>= 1) v = fmaxf(v, __shfl_xor(v, o));
        if ((j & 63) == 0) { red_sh[w] = v; p_sh[0][w] = g; }
    }
    __syncthreads();
    {
        float mm = fmaxf(red_sh[0], red_sh[1]);
        float ev = __expf(alpha - mm);
        #pragma unroll
        for (int o = 32; o > 0; o >>= 1) ev += __shfl_xor(ev, o);
        if ((j & 63) == 0) red_sh[2 + w] = ev;
        __syncthreads();
        if (j == 0) {
            float part = mm + __logf(red_sh[2] + red_sh[3]);
            float gtot = p_sh[0][0] + p_sh[0][1];
            atomicAdd(out, part - gtot);
        }
    }
}

extern "C" void kernel_launch(void* const* d_in, const int* in_sizes, int n_in,
                              void* d_out, int out_size, void* d_ws, size_t ws_size,
                              hipStream_t stream) {
    const float*         emissions = (const float*)d_in[0];
    const int*           tags      = (const int*)d_in[1];
    const unsigned char* mask      = (const unsigned char*)d_in[2];
    const float*         trans     = (const float*)d_in[3];
    float*               out       = (float*)d_out;

    zero_out_kernel<<<1, 1, 0, stream>>>(out);
    crf_fwd_kernel<<<BB, 128, 0, stream>>>(emissions, tags, mask, trans, out);
}